// Round 1
// baseline (479.969 us; speedup 1.0000x reference)
//
#include <hip/hip_runtime.h>
#include <hip/hip_bf16.h>

typedef short bf16x8 __attribute__((ext_vector_type(8)));
typedef float f32x4 __attribute__((ext_vector_type(4)));

__device__ __forceinline__ unsigned short f2bf(float f) {
  union { float f; unsigned int u; } x; x.f = f;
  return (unsigned short)((x.u + 0x7fffu + ((x.u >> 16) & 1u)) >> 16);
}
__device__ __forceinline__ float bf2f(unsigned short u) {
  union { unsigned int u; float f; } x; x.u = ((unsigned int)u) << 16;
  return x.f;
}
__device__ __forceinline__ void gload_lds16(const void* g, void* l) {
  __builtin_amdgcn_global_load_lds((const __attribute__((address_space(1))) void*)g,
                                   (__attribute__((address_space(3))) void*)l, 16, 0, 0);
}

// ---------------- cast x (f32 -> bf16), 4 elems/thread ----------------
__global__ void cast_f32_bf16(const float* __restrict__ src, unsigned short* __restrict__ dst) {
  int i = blockIdx.x * blockDim.x + threadIdx.x;
  float4 v = reinterpret_cast<const float4*>(src)[i];
  ushort4 o;
  o.x = f2bf(v.x); o.y = f2bf(v.y); o.z = f2bf(v.z); o.w = f2bf(v.w);
  reinterpret_cast<ushort4*>(dst)[i] = o;
}

// ------------- transpose+cast: src (R x C) f32 -> dst (C x R) bf16 -------------
__global__ void transpose_cast(const float* __restrict__ src, unsigned short* __restrict__ dst,
                               int R, int C) {
  __shared__ float tile[32][33];
  int c0 = blockIdx.x * 32, r0 = blockIdx.y * 32;
  int tx = threadIdx.x, ty = threadIdx.y;  // 32 x 8
#pragma unroll
  for (int i = 0; i < 4; ++i)
    tile[ty + i * 8][tx] = src[(size_t)(r0 + ty + i * 8) * C + (c0 + tx)];
  __syncthreads();
#pragma unroll
  for (int i = 0; i < 4; ++i)
    dst[(size_t)(c0 + ty + i * 8) * R + (r0 + tx)] = f2bf(tile[tx][ty + i * 8]);
}

// ---------------- m97-style 128x128 GEMM, A (MxK) * Bt (NxK), bf16 in ----------------
// EPI 0: write bf16 split into Q/K/V (B,T,D) contiguous buffers (QKV gemm, N=6144)
// EPI 1: write f32 + bias (proj gemm)
template <int EPI>
__global__ __launch_bounds__(256, 2)
void gemm_bt(const unsigned short* __restrict__ A, const unsigned short* __restrict__ Bt,
             unsigned short* __restrict__ Qo, unsigned short* __restrict__ Ko,
             unsigned short* __restrict__ Vo, float* __restrict__ Cf,
             const float* __restrict__ bias, int M, int N, int K) {
  __shared__ __align__(16) unsigned short lA[128 * 32];
  __shared__ __align__(16) unsigned short lB[128 * 32];
  const int tid = threadIdx.x;
  const int lane = tid & 63, wid = tid >> 6;
  const int wr = wid >> 1, wc = wid & 1;

  // XCD-bijective swizzle (gridDim.x % 8 == 0 for both shapes)
  const int nbn = N >> 7;
  const int cpx = gridDim.x >> 3;
  const int id = blockIdx.x;
  const int sw = (id & 7) * cpx + (id >> 3);
  const int bm = sw / nbn, bn = sw % nbn;
  const int row0 = bm << 7, col0 = bn << 7;

  // staging addresses: 2 issues x 16B per thread per tile (128x32 bf16 = 8KB)
  const int srow = tid >> 2, scol = (tid & 3) << 3;
  const unsigned short* gA0 = A + (size_t)(row0 + srow) * K + scol;
  const unsigned short* gA1 = gA0 + (size_t)64 * K;
  const unsigned short* gB0 = Bt + (size_t)(col0 + srow) * K + scol;
  const unsigned short* gB1 = gB0 + (size_t)64 * K;
  unsigned short* lA0 = &lA[tid * 8];
  unsigned short* lA1 = &lA[2048 + tid * 8];
  unsigned short* lB0 = &lB[tid * 8];
  unsigned short* lB1 = &lB[2048 + tid * 8];

  const int fr = lane & 15;          // fragment row (A) / col (B)
  const int fk = (lane >> 4) << 3;   // k-chunk (8 elems)

  f32x4 acc[4][4] = {};

  for (int k0 = 0; k0 < K; k0 += 32) {
    gload_lds16(gA0 + k0, lA0);
    gload_lds16(gA1 + k0, lA1);
    gload_lds16(gB0 + k0, lB0);
    gload_lds16(gB1 + k0, lB1);
    __syncthreads();
    bf16x8 a[4], b[4];
#pragma unroll
    for (int m = 0; m < 4; ++m)
      a[m] = *reinterpret_cast<const bf16x8*>(&lA[(wr * 64 + m * 16 + fr) * 32 + fk]);
#pragma unroll
    for (int n = 0; n < 4; ++n)
      b[n] = *reinterpret_cast<const bf16x8*>(&lB[(wc * 64 + n * 16 + fr) * 32 + fk]);
#pragma unroll
    for (int m = 0; m < 4; ++m)
#pragma unroll
      for (int n = 0; n < 4; ++n)
        acc[m][n] = __builtin_amdgcn_mfma_f32_16x16x32_bf16(a[m], b[n], acc[m][n], 0, 0, 0);
    __syncthreads();
  }

  // epilogue: C/D layout col = lane&15, row = (lane>>4)*4 + r  [m89/m91]
  const int crow0 = row0 + wr * 64 + ((lane >> 4) << 2);
  const int ccol0 = col0 + wc * 64 + fr;
#pragma unroll
  for (int m = 0; m < 4; ++m) {
#pragma unroll
    for (int n = 0; n < 4; ++n) {
      const int col = ccol0 + n * 16;
#pragma unroll
      for (int r = 0; r < 4; ++r) {
        const int row = crow0 + m * 16 + r;
        const float v = acc[m][n][r];
        if (EPI == 0) {
          const int seg = col >> 11, cc = col & 2047;
          unsigned short* dst = (seg == 0) ? Qo : (seg == 1 ? Ko : Vo);
          dst[(size_t)row * 2048 + cc] = f2bf(v);
        } else {
          Cf[(size_t)row * N + col] = v + bias[col];
        }
      }
    }
  }
}

// --------- attention diag + V scale, one head strip (64 t-rows) per block ---------
// Q,K,V: contiguous (B,T,D) bf16 -> head (b,n) is contiguous (2048,128) row-major.
// Computes diag[t] = exp(s_tt)/sum_j exp(s_tj), s = Q K^T / sqrt(2048), then
// OV[b*T+t, n*128+h] = diag[t] * V_head[t,h] (bf16).
__global__ __launch_bounds__(256, 2)
void attn_diag_ov(const unsigned short* __restrict__ Q, const unsigned short* __restrict__ K,
                  const unsigned short* __restrict__ V, unsigned short* __restrict__ OV) {
  __shared__ __align__(16) unsigned short qs[64 * 128];
  __shared__ __align__(16) unsigned short ks[128 * 128];
  __shared__ float dlds[64];
  const int tid = threadIdx.x;
  const int lane = tid & 63, wid = tid >> 6;
  const int head = blockIdx.y;            // b*16 + n
  const int b = head >> 4, n = head & 15;
  const int t0 = blockIdx.x << 6;
  const size_t hoff = (size_t)head << 18; // head * 2048*128
  const unsigned short* Qh = Q + hoff;
  const unsigned short* Kh = K + hoff;
  const unsigned short* Vh = V + hoff;

  // stage Q strip (64x128 bf16 = 16KB), source pre-swizzled so reads can XOR-deswizzle
  const char* qsrc = (const char*)(Qh + ((size_t)t0 << 7));
#pragma unroll
  for (int i = 0; i < 4; ++i) {
    const int fb = (i * 256 + tid) << 4;
    const int sb = fb ^ (((fb >> 8) & 7) << 4);
    gload_lds16(qsrc + sb, (char*)qs + fb);
  }

  const int fr = lane & 15;
  const int fkb = (lane >> 4) << 4;  // byte offset of 16B k-chunk
  const int g4 = (lane >> 4) << 2;

  float rsum[4] = {0.f, 0.f, 0.f, 0.f};
  float dnum[4] = {0.f, 0.f, 0.f, 0.f};
  const float scale = 0.02209708691207961f;  // 1/sqrt(2048)
  bf16x8 afrag[4];

  for (int jc = 0; jc < 2048; jc += 128) {
    const char* ksrc = (const char*)(Kh + ((size_t)jc << 7));
#pragma unroll
    for (int i = 0; i < 8; ++i) {
      const int fb = (i * 256 + tid) << 4;
      const int sb = fb ^ (((fb >> 8) & 7) << 4);
      gload_lds16(ksrc + sb, (char*)ks + fb);
    }
    __syncthreads();
    if (jc == 0) {  // Q frags are loop-invariant: load once
#pragma unroll
      for (int kk = 0; kk < 4; ++kk) {
        const int row = wid * 16 + fr;
        const int byte = (row << 8) + (kk << 6) + fkb;
        afrag[kk] = *reinterpret_cast<const bf16x8*>((const char*)qs + (byte ^ ((row & 7) << 4)));
      }
    }
#pragma unroll
    for (int jt = 0; jt < 8; ++jt) {
      f32x4 acc = {0.f, 0.f, 0.f, 0.f};
#pragma unroll
      for (int kk = 0; kk < 4; ++kk) {
        const int row = jt * 16 + fr;
        const int byte = (row << 8) + (kk << 6) + fkb;
        bf16x8 bfrag = *reinterpret_cast<const bf16x8*>((const char*)ks + (byte ^ ((row & 7) << 4)));
        acc = __builtin_amdgcn_mfma_f32_16x16x32_bf16(afrag[kk], bfrag, acc, 0, 0, 0);
      }
      const int colj = jc + jt * 16 + fr;
      const int rowt = t0 + wid * 16 + g4;
#pragma unroll
      for (int r = 0; r < 4; ++r) {
        const float e = __expf(acc[r] * scale);
        rsum[r] += e;
        if (colj == rowt + r) dnum[r] = e;  // diagonal hit (exactly once per row)
      }
    }
    __syncthreads();
  }

  // reduce across the 16 lanes holding different columns
#pragma unroll
  for (int r = 0; r < 4; ++r) {
#pragma unroll
    for (int s = 1; s < 16; s <<= 1) {
      rsum[r] += __shfl_xor(rsum[r], s, 64);
      dnum[r] += __shfl_xor(dnum[r], s, 64);
    }
  }
  if (fr == 0) {
#pragma unroll
    for (int r = 0; r < 4; ++r)
      dlds[wid * 16 + g4 + r] = dnum[r] / rsum[r];
  }
  __syncthreads();

  // OV write: rows t0..t0+63, cols n*128..+128 of OV (8192 x 2048), vectorized
  const unsigned short* vsrc = Vh + ((size_t)t0 << 7);
  unsigned short* dst = OV + ((size_t)((b << 11) + t0)) * 2048 + (n << 7);
#pragma unroll
  for (int c = 0; c < 4; ++c) {
    const int flat = (c * 256 + tid) << 3;
    const int row = flat >> 7, col = flat & 127;
    bf16x8 v = *reinterpret_cast<const bf16x8*>(vsrc + flat);
    const float d = dlds[row];
    bf16x8 o;
#pragma unroll
    for (int e = 0; e < 8; ++e)
      o[e] = (short)f2bf(bf2f((unsigned short)v[e]) * d);
    *reinterpret_cast<bf16x8*>(dst + (size_t)row * 2048 + col) = o;
  }
}

extern "C" void kernel_launch(void* const* d_in, const int* in_sizes, int n_in,
                              void* d_out, int out_size, void* d_ws, size_t ws_size,
                              hipStream_t stream) {
  const float* x = (const float*)d_in[0];        // (4,2048,2048)
  const float* w_qkv = (const float*)d_in[1];    // (2048,6144)
  const float* w_proj = (const float*)d_in[2];   // (2048,2048)
  const float* b_proj = (const float*)d_in[3];   // (2048,)
  float* out = (float*)d_out;                    // (4,2048,2048) f32

  char* p = (char*)d_ws;
  unsigned short* Xb = (unsigned short*)p;     p += (size_t)8192 * 2048 * 2;
  unsigned short* WqkvT = (unsigned short*)p;  p += (size_t)6144 * 2048 * 2;
  unsigned short* WprojT = (unsigned short*)p; p += (size_t)2048 * 2048 * 2;
  unsigned short* Qb = (unsigned short*)p;     p += (size_t)8192 * 2048 * 2;
  unsigned short* Kb = (unsigned short*)p;     p += (size_t)8192 * 2048 * 2;
  unsigned short* Vb = (unsigned short*)p;     p += (size_t)8192 * 2048 * 2;
  unsigned short* OV = (unsigned short*)p;     p += (size_t)8192 * 2048 * 2;
  // total 192 MiB of d_ws

  cast_f32_bf16<<<16384, 256, 0, stream>>>(x, Xb);
  transpose_cast<<<dim3(192, 64), dim3(32, 8), 0, stream>>>(w_qkv, WqkvT, 2048, 6144);
  transpose_cast<<<dim3(64, 64), dim3(32, 8), 0, stream>>>(w_proj, WprojT, 2048, 2048);

  // QKV = Xb (8192x2048) * WqkvT^T -> split bf16 Q/K/V (B,T,D)
  gemm_bt<0><<<dim3(64 * 48), 256, 0, stream>>>(Xb, WqkvT, Qb, Kb, Vb, nullptr, nullptr,
                                                8192, 6144, 2048);
  // diag softmax + V scale -> OV (8192x2048) bf16
  attn_diag_ov<<<dim3(32, 64), 256, 0, stream>>>(Qb, Kb, Vb, OV);
  // out = OV * WprojT^T + b_proj (f32)
  gemm_bt<1><<<dim3(64 * 16), 256, 0, stream>>>(OV, WprojT, nullptr, nullptr, nullptr, out,
                                                b_proj, 8192, 2048, 2048);
}

// Round 3
// 428.274 us; speedup vs baseline: 1.1207x; 1.1207x over previous
//
#include <hip/hip_runtime.h>
#include <hip/hip_bf16.h>

typedef short bf16x8 __attribute__((ext_vector_type(8)));
typedef float f32x4 __attribute__((ext_vector_type(4)));

__device__ __forceinline__ unsigned short f2bf(float f) {
  union { float f; unsigned int u; } x; x.f = f;
  return (unsigned short)((x.u + 0x7fffu + ((x.u >> 16) & 1u)) >> 16);
}
__device__ __forceinline__ float bf2f(unsigned short u) {
  union { unsigned int u; float f; } x; x.u = ((unsigned int)u) << 16;
  return x.f;
}
__device__ __forceinline__ void gload_lds16(const void* g, void* l) {
  __builtin_amdgcn_global_load_lds((const __attribute__((address_space(1))) void*)g,
                                   (__attribute__((address_space(3))) void*)l, 16, 0, 0);
}

// ---------------- cast x (f32 -> bf16), 4 elems/thread ----------------
__global__ void cast_f32_bf16(const float* __restrict__ src, unsigned short* __restrict__ dst) {
  int i = blockIdx.x * blockDim.x + threadIdx.x;
  float4 v = reinterpret_cast<const float4*>(src)[i];
  ushort4 o;
  o.x = f2bf(v.x); o.y = f2bf(v.y); o.z = f2bf(v.z); o.w = f2bf(v.w);
  reinterpret_cast<ushort4*>(dst)[i] = o;
}

// ------------- transpose+cast: src (R x C) f32 -> dst (C x R) bf16 -------------
__global__ void transpose_cast(const float* __restrict__ src, unsigned short* __restrict__ dst,
                               int R, int C) {
  __shared__ float tile[32][33];
  int c0 = blockIdx.x * 32, r0 = blockIdx.y * 32;
  int tx = threadIdx.x, ty = threadIdx.y;  // 32 x 8
#pragma unroll
  for (int i = 0; i < 4; ++i)
    tile[ty + i * 8][tx] = src[(size_t)(r0 + ty + i * 8) * C + (c0 + tx)];
  __syncthreads();
#pragma unroll
  for (int i = 0; i < 4; ++i)
    dst[(size_t)(c0 + ty + i * 8) * R + (r0 + tx)] = f2bf(tile[tx][ty + i * 8]);
}

// ================= 256x256 8-phase GEMM (T2+T3+T4+T5), A (MxK) * Bt (NxK) =================
// 512 threads = 8 waves (2M x 4N). BK=64. LDS 128 KiB dynamic:
//   buf(t&1)*64KB + { A half0 | A half1 | B half0 | B half1 }, 16 KB each ([128 rows][128 B]).
// Swizzle: LDS(row r, 16B-slot s) holds global chunk s ^ (r&7)  (conflict-free ds_read_b128).
// Stage stream j = 4*t + ht, ht: 0=A.h0 1=B.h0 2=B.h1 3=A.h1 (first-reader order).
// Iter k phase p stages j=4(k+1)+p -> always the OTHER buffer (no WAR with live reads).
// Per-phase vmcnt(4) = <=2 halves in flight; every half's first reader is >=3 phases
// after issue, so all reads covered. Tail: vmcnt(2)/vmcnt(0) at k=NT-1 p0/p1.
// EPI 0: bf16 split into Q/K/V (B,T,D). EPI 1: f32 + bias.
template <int EPI>
__global__ __launch_bounds__(512, 2)
void gemm256(const unsigned short* __restrict__ A, const unsigned short* __restrict__ Bt,
             unsigned short* __restrict__ Qo, unsigned short* __restrict__ Ko,
             unsigned short* __restrict__ Vo, float* __restrict__ Cf,
             const float* __restrict__ bias, int M, int N, int K) {
  extern __shared__ __align__(16) char lds[];
  const int tid = threadIdx.x;
  const int lane = tid & 63, wid = tid >> 6;
  const int wm = wid >> 2, wn = wid & 3;
  const int fr = lane & 15, fq = lane >> 4;

  // XCD swizzle (gridDim.x % 8 == 0 for both shapes)
  const int nbn = N >> 8;
  const int cpx = gridDim.x >> 3;
  const int id = blockIdx.x;
  const int sw = (id & 7) * cpx + (id >> 3);
  const int bm = sw / nbn, bn = sw % nbn;
  const int row0 = bm << 8, col0 = bn << 8;

  const int NT = K >> 6;

  // staging: thread covers row srow (+64 for 2nd issue), 16B at XOR-swizzled col
  const int srow = tid >> 3;
  const int scol = ((tid & 7) ^ (srow & 7)) << 3;  // elems

  auto stage = [&](int j) {
    if (j >= 4 * NT) return;
    const int t = j >> 2, ht = j & 3;
    const int isB = (ht == 1 || ht == 2);
    const int h = (ht >= 2) ? 1 : 0;
    const unsigned short* base = isB ? Bt : A;
    const int grow = (isB ? col0 : row0) + h * 128 + srow;
    const unsigned short* src = base + (size_t)grow * K + t * 64 + scol;
    char* ldst = lds + ((size_t)(t & 1) << 16) + (isB ? 32768 : 0) + (h << 14) + tid * 16;
    gload_lds16(src, ldst);
    gload_lds16(src + (size_t)64 * K, ldst + 8192);
  };

  f32x4 acc[2][4][2][2] = {};

  // prologue: tile 0 fully staged, full drain, barrier
#pragma unroll
  for (int j = 0; j < 4; ++j) stage(j);
  asm volatile("s_waitcnt vmcnt(0)" ::: "memory");
  asm volatile("s_barrier" ::: "memory");

  for (int k = 0; k < NT; ++k) {
    const char* bufb = lds + ((size_t)(k & 1) << 16);
#pragma unroll
    for (int p = 0; p < 4; ++p) {
      const int mh = p >> 1, nh = p & 1;
      const char* Ab = bufb + (mh << 14);
      const char* Bb = bufb + 32768 + (nh << 14);
      bf16x8 a[4][2], b[2][2];
#pragma unroll
      for (int i2 = 0; i2 < 4; ++i2)
#pragma unroll
        for (int ks = 0; ks < 2; ++ks) {
          const int byte = ((((wm * 4 + i2) * 16 + fr) * 128) + ks * 64 + fq * 16) ^ ((fr & 7) << 4);
          a[i2][ks] = *reinterpret_cast<const bf16x8*>(Ab + byte);
        }
#pragma unroll
      for (int j2 = 0; j2 < 2; ++j2)
#pragma unroll
        for (int ks = 0; ks < 2; ++ks) {
          const int byte = ((((wn * 2 + j2) * 16 + fr) * 128) + ks * 64 + fq * 16) ^ ((fr & 7) << 4);
          b[j2][ks] = *reinterpret_cast<const bf16x8*>(Bb + byte);
        }
      stage(4 * (k + 1) + p);
      if (k < NT - 1) {
        asm volatile("s_waitcnt vmcnt(4)" ::: "memory");
      } else {
        if (p == 0) asm volatile("s_waitcnt vmcnt(2)" ::: "memory");
        if (p == 1) asm volatile("s_waitcnt vmcnt(0)" ::: "memory");
      }
      asm volatile("s_barrier" ::: "memory");
      __builtin_amdgcn_s_setprio(1);
#pragma unroll
      for (int i2 = 0; i2 < 4; ++i2)
#pragma unroll
        for (int j2 = 0; j2 < 2; ++j2)
#pragma unroll
          for (int ks = 0; ks < 2; ++ks)
            acc[mh][i2][nh][j2] =
                __builtin_amdgcn_mfma_f32_16x16x32_bf16(a[i2][ks], b[j2][ks], acc[mh][i2][nh][j2], 0, 0, 0);
      __builtin_amdgcn_s_setprio(0);
      asm volatile("s_barrier" ::: "memory");
    }
  }

  // epilogue: C/D layout col = lane&15, row = (lane>>4)*4 + r
#pragma unroll
  for (int mh = 0; mh < 2; ++mh)
#pragma unroll
    for (int i2 = 0; i2 < 4; ++i2) {
      const int rbase = row0 + (mh * 8 + wm * 4 + i2) * 16 + fq * 4;
#pragma unroll
      for (int nh = 0; nh < 2; ++nh)
#pragma unroll
        for (int j2 = 0; j2 < 2; ++j2) {
          const int col = col0 + (nh * 8 + wn * 2 + j2) * 16 + fr;
#pragma unroll
          for (int r = 0; r < 4; ++r) {
            const float v = acc[mh][i2][nh][j2][r];
            const int row = rbase + r;
            if (EPI == 0) {
              const int seg = col >> 11, cc = col & 2047;
              unsigned short* dst = (seg == 0) ? Qo : (seg == 1 ? Ko : Vo);
              dst[(size_t)row * 2048 + cc] = f2bf(v);
            } else {
              Cf[(size_t)row * N + col] = v + bias[col];
            }
          }
        }
    }
}

// --------- attention diag + V scale, one head strip (64 t-rows) per block ---------
__global__ __launch_bounds__(256, 2)
void attn_diag_ov(const unsigned short* __restrict__ Q, const unsigned short* __restrict__ K,
                  const unsigned short* __restrict__ V, unsigned short* __restrict__ OV) {
  __shared__ __align__(16) unsigned short qs[64 * 128];
  __shared__ __align__(16) unsigned short ks[128 * 128];
  __shared__ float dlds[64];
  const int tid = threadIdx.x;
  const int lane = tid & 63, wid = tid >> 6;
  const int head = blockIdx.y;            // b*16 + n
  const int b = head >> 4, n = head & 15;
  const int t0 = blockIdx.x << 6;
  const size_t hoff = (size_t)head << 18;
  const unsigned short* Qh = Q + hoff;
  const unsigned short* Kh = K + hoff;
  const unsigned short* Vh = V + hoff;

  const char* qsrc = (const char*)(Qh + ((size_t)t0 << 7));
#pragma unroll
  for (int i = 0; i < 4; ++i) {
    const int fb = (i * 256 + tid) << 4;
    const int sb = fb ^ (((fb >> 8) & 7) << 4);
    gload_lds16(qsrc + sb, (char*)qs + fb);
  }

  const int fr = lane & 15;
  const int fkb = (lane >> 4) << 4;
  const int g4 = (lane >> 4) << 2;

  float rsum[4] = {0.f, 0.f, 0.f, 0.f};
  float dnum[4] = {0.f, 0.f, 0.f, 0.f};
  const float scale = 0.02209708691207961f;  // 1/sqrt(2048)
  bf16x8 afrag[4];

  for (int jc = 0; jc < 2048; jc += 128) {
    const char* ksrc = (const char*)(Kh + ((size_t)jc << 7));
#pragma unroll
    for (int i = 0; i < 8; ++i) {
      const int fb = (i * 256 + tid) << 4;
      const int sb = fb ^ (((fb >> 8) & 7) << 4);
      gload_lds16(ksrc + sb, (char*)ks + fb);
    }
    __syncthreads();
    if (jc == 0) {
#pragma unroll
      for (int kk = 0; kk < 4; ++kk) {
        const int row = wid * 16 + fr;
        const int byte = (row << 8) + (kk << 6) + fkb;
        afrag[kk] = *reinterpret_cast<const bf16x8*>((const char*)qs + (byte ^ ((row & 7) << 4)));
      }
    }
#pragma unroll
    for (int jt = 0; jt < 8; ++jt) {
      f32x4 acc = {0.f, 0.f, 0.f, 0.f};
#pragma unroll
      for (int kk = 0; kk < 4; ++kk) {
        const int row = jt * 16 + fr;
        const int byte = (row << 8) + (kk << 6) + fkb;
        bf16x8 bfrag = *reinterpret_cast<const bf16x8*>((const char*)ks + (byte ^ ((row & 7) << 4)));
        acc = __builtin_amdgcn_mfma_f32_16x16x32_bf16(afrag[kk], bfrag, acc, 0, 0, 0);
      }
      const int colj = jc + jt * 16 + fr;
      const int rowt = t0 + wid * 16 + g4;
#pragma unroll
      for (int r = 0; r < 4; ++r) {
        const float e = __expf(acc[r] * scale);
        rsum[r] += e;
        if (colj == rowt + r) dnum[r] = e;
      }
    }
    __syncthreads();
  }

#pragma unroll
  for (int r = 0; r < 4; ++r) {
#pragma unroll
    for (int s = 1; s < 16; s <<= 1) {
      rsum[r] += __shfl_xor(rsum[r], s, 64);
      dnum[r] += __shfl_xor(dnum[r], s, 64);
    }
  }
  if (fr == 0) {
#pragma unroll
    for (int r = 0; r < 4; ++r)
      dlds[wid * 16 + g4 + r] = dnum[r] / rsum[r];
  }
  __syncthreads();

  const unsigned short* vsrc = Vh + ((size_t)t0 << 7);
  unsigned short* dst = OV + ((size_t)((b << 11) + t0)) * 2048 + (n << 7);
#pragma unroll
  for (int c = 0; c < 4; ++c) {
    const int flat = (c * 256 + tid) << 3;
    const int row = flat >> 7, col = flat & 127;
    bf16x8 v = *reinterpret_cast<const bf16x8*>(vsrc + flat);
    const float d = dlds[row];
    bf16x8 o;
#pragma unroll
    for (int e = 0; e < 8; ++e)
      o[e] = (short)f2bf(bf2f((unsigned short)v[e]) * d);
    *reinterpret_cast<bf16x8*>(dst + (size_t)row * 2048 + col) = o;
  }
}

extern "C" void kernel_launch(void* const* d_in, const int* in_sizes, int n_in,
                              void* d_out, int out_size, void* d_ws, size_t ws_size,
                              hipStream_t stream) {
  const float* x = (const float*)d_in[0];        // (4,2048,2048)
  const float* w_qkv = (const float*)d_in[1];    // (2048,6144)
  const float* w_proj = (const float*)d_in[2];   // (2048,2048)
  const float* b_proj = (const float*)d_in[3];   // (2048,)
  float* out = (float*)d_out;                    // (4,2048,2048) f32

  char* p = (char*)d_ws;
  unsigned short* Xb = (unsigned short*)p;     p += (size_t)8192 * 2048 * 2;
  unsigned short* WqkvT = (unsigned short*)p;  p += (size_t)6144 * 2048 * 2;
  unsigned short* WprojT = (unsigned short*)p; p += (size_t)2048 * 2048 * 2;
  unsigned short* Qb = (unsigned short*)p;     p += (size_t)8192 * 2048 * 2;
  unsigned short* Kb = (unsigned short*)p;     p += (size_t)8192 * 2048 * 2;
  unsigned short* Vb = (unsigned short*)p;     p += (size_t)8192 * 2048 * 2;
  unsigned short* OV = (unsigned short*)p;     p += (size_t)8192 * 2048 * 2;

  // allow 128 KiB dynamic LDS (persistent function attribute; safe to repeat)
  (void)hipFuncSetAttribute((const void*)gemm256<0>,
                            hipFuncAttributeMaxDynamicSharedMemorySize, 131072);
  (void)hipFuncSetAttribute((const void*)gemm256<1>,
                            hipFuncAttributeMaxDynamicSharedMemorySize, 131072);

  cast_f32_bf16<<<16384, 256, 0, stream>>>(x, Xb);
  transpose_cast<<<dim3(192, 64), dim3(32, 8), 0, stream>>>(w_qkv, WqkvT, 2048, 6144);
  transpose_cast<<<dim3(64, 64), dim3(32, 8), 0, stream>>>(w_proj, WprojT, 2048, 2048);

  // QKV = Xb (8192x2048) * WqkvT^T -> split bf16 Q/K/V (B,T,D)
  gemm256<0><<<dim3(32 * 24), 512, 131072, stream>>>(Xb, WqkvT, Qb, Kb, Vb, nullptr, nullptr,
                                                     8192, 6144, 2048);
  // diag softmax + V scale -> OV (8192x2048) bf16
  attn_diag_ov<<<dim3(32, 64), 256, 0, stream>>>(Qb, Kb, Vb, OV);
  // out = OV * WprojT^T + b_proj (f32)
  gemm256<1><<<dim3(32 * 8), 512, 131072, stream>>>(OV, WprojT, nullptr, nullptr, nullptr, out,
                                                    b_proj, 8192, 2048, 2048);
}

// Round 4
// 412.461 us; speedup vs baseline: 1.1637x; 1.0383x over previous
//
#include <hip/hip_runtime.h>
#include <hip/hip_bf16.h>

typedef short bf16x8 __attribute__((ext_vector_type(8)));
typedef float f32x4 __attribute__((ext_vector_type(4)));

__device__ __forceinline__ unsigned short f2bf(float f) {
  union { float f; unsigned int u; } x; x.f = f;
  return (unsigned short)((x.u + 0x7fffu + ((x.u >> 16) & 1u)) >> 16);
}
__device__ __forceinline__ float bf2f(unsigned short u) {
  union { unsigned int u; float f; } x; x.u = ((unsigned int)u) << 16;
  return x.f;
}
__device__ __forceinline__ void gload_lds16(const void* g, void* l) {
  __builtin_amdgcn_global_load_lds((const __attribute__((address_space(1))) void*)g,
                                   (__attribute__((address_space(3))) void*)l, 16, 0, 0);
}

// ---------------- cast x (f32 -> bf16), 4 elems/thread ----------------
__global__ void cast_f32_bf16(const float* __restrict__ src, unsigned short* __restrict__ dst) {
  int i = blockIdx.x * blockDim.x + threadIdx.x;
  float4 v = reinterpret_cast<const float4*>(src)[i];
  ushort4 o;
  o.x = f2bf(v.x); o.y = f2bf(v.y); o.z = f2bf(v.z); o.w = f2bf(v.w);
  reinterpret_cast<ushort4*>(dst)[i] = o;
}

// ------------- transpose+cast: src (R x C) f32 -> dst (C x R) bf16 -------------
__global__ void transpose_cast(const float* __restrict__ src, unsigned short* __restrict__ dst,
                               int R, int C) {
  __shared__ float tile[32][33];
  int c0 = blockIdx.x * 32, r0 = blockIdx.y * 32;
  int tx = threadIdx.x, ty = threadIdx.y;  // 32 x 8
#pragma unroll
  for (int i = 0; i < 4; ++i)
    tile[ty + i * 8][tx] = src[(size_t)(r0 + ty + i * 8) * C + (c0 + tx)];
  __syncthreads();
#pragma unroll
  for (int i = 0; i < 4; ++i)
    dst[(size_t)(c0 + ty + i * 8) * R + (r0 + tx)] = f2bf(tile[tx][ty + i * 8]);
}

// ============ 256x256 GEMM, half-tile RING-7 pipeline (T2+T3/T4-deep+T5) ============
// 512 threads = 8 waves (2M x 4N). BK=64. LDS = 8 slots x 16 KB = 128 KiB dynamic.
// Half-tile stream j = 4t+ht, ht: 0=A.h0 1=B.h0 2=B.h1 3=A.h1 (first-reader order).
// Half j -> slot j%7, staged at global phase j-5 (phase = 4k+p). Slot 7 = scratch for
// tail dummy stages (keeps vmcnt counting uniform; drained by vmcnt(0) after loop).
// Liveness: overwriter j+7 staged at phase (last read of j)+1 or later, and phases are
// barrier-separated -> no WAR. Max live halves = 7 (exactly the ring).
// Every read's operand was issued >=4 phases earlier; per-phase vmcnt(6) (3 halves in
// flight) forces issues >=4 phases old to have landed -> HBM latency covered by ~4
// phases of MFMA instead of 2.
// Fragment reuse: a cached p0->p1 / p2->p3; b0 cached p0->p2; b1 cached p1->p3
// (24 ds_read_b128/tile instead of 48).
// Swizzle (T2): within a slot, row r (128B) holds 16B-chunk s at byte (s^(r&7))*16;
// staging pre-swizzles the global source column, reads XOR the byte offset.
// EPI 0: bf16 split into Q/K/V (B,T,D). EPI 1: f32 + bias.
template <int EPI>
__global__ __launch_bounds__(512, 2)
void gemm256(const unsigned short* __restrict__ A, const unsigned short* __restrict__ Bt,
             unsigned short* __restrict__ Qo, unsigned short* __restrict__ Ko,
             unsigned short* __restrict__ Vo, float* __restrict__ Cf,
             const float* __restrict__ bias, int M, int N, int K) {
  extern __shared__ __align__(16) char lds[];
  const int tid = threadIdx.x;
  const int lane = tid & 63, wid = tid >> 6;
  const int wm = wid >> 2, wn = wid & 3;
  const int fr = lane & 15, fq = lane >> 4;

  // XCD swizzle (gridDim.x % 8 == 0 for both shapes)
  const int nbn = N >> 8;
  const int cpx = gridDim.x >> 3;
  const int id = blockIdx.x;
  const int sw = (id & 7) * cpx + (id >> 3);
  const int bm = sw / nbn, bn = sw % nbn;
  const int row0 = bm << 8, col0 = bn << 8;

  const int NT = K >> 6;

  // staging: thread covers row srow (+64 for 2nd issue), 16B at XOR-pre-swizzled col
  const int srow = tid >> 3;
  const int scol = ((tid & 7) ^ (srow & 7)) << 3;  // elems

  auto stage = [&](int j, int slot) {
    if (j < 4 * NT) {
      const int t = j >> 2, ht = j & 3;
      const int isB = (ht == 1 || ht == 2);
      const int h = (ht >= 2) ? 1 : 0;
      const unsigned short* base = isB ? Bt : A;
      const int grow = (isB ? col0 : row0) + h * 128 + srow;
      const unsigned short* src = base + (size_t)grow * K + t * 64 + scol;
      char* l0 = lds + slot * 16384 + tid * 16;
      gload_lds16(src, l0);
      gload_lds16(src + (size_t)64 * K, l0 + 8192);
    } else {
      // tail dummy: keep vmcnt stream uniform; lands in scratch slot 7
      char* l0 = lds + 7 * 16384 + tid * 16;
      gload_lds16(A + (tid << 3), l0);
      gload_lds16(A + (tid << 3), l0 + 8192);
    }
  };

  f32x4 acc[2][4][2][2] = {};

  // prologue: halves j=0..4 -> slots 0..4; force j=0,1 landed (reads of phase 0)
  stage(0, 0); stage(1, 1); stage(2, 2); stage(3, 3); stage(4, 4);
  asm volatile("s_waitcnt vmcnt(6)" ::: "memory");
  asm volatile("s_barrier" ::: "memory");

  int sA0 = 0, sB0 = 1, sB1 = 2, sA1 = 3, sst = 5;

  for (int k = 0; k < NT; ++k) {
    const int j0 = 4 * k + 5;
    bf16x8 a[4][2], b0[2][2], b1[2][2];

    // ---- phase 0: (mh=0, nh=0) — read a(h0), b0(h0) ----
    {
      const char* Ab = lds + sA0 * 16384;
      const char* Bb = lds + sB0 * 16384;
#pragma unroll
      for (int i2 = 0; i2 < 4; ++i2)
#pragma unroll
        for (int ks = 0; ks < 2; ++ks) {
          const int byte = ((((wm * 4 + i2) * 16 + fr) * 128) + ks * 64 + fq * 16) ^ ((fr & 7) << 4);
          a[i2][ks] = *reinterpret_cast<const bf16x8*>(Ab + byte);
        }
#pragma unroll
      for (int j2 = 0; j2 < 2; ++j2)
#pragma unroll
        for (int ks = 0; ks < 2; ++ks) {
          const int byte = ((((wn * 2 + j2) * 16 + fr) * 128) + ks * 64 + fq * 16) ^ ((fr & 7) << 4);
          b0[j2][ks] = *reinterpret_cast<const bf16x8*>(Bb + byte);
        }
      stage(j0 + 0, sst); sst = (sst == 6) ? 0 : sst + 1;
      asm volatile("s_waitcnt vmcnt(6)" ::: "memory");
      asm volatile("s_barrier" ::: "memory");
      __builtin_amdgcn_sched_barrier(0);
      __builtin_amdgcn_s_setprio(1);
#pragma unroll
      for (int i2 = 0; i2 < 4; ++i2)
#pragma unroll
        for (int j2 = 0; j2 < 2; ++j2)
#pragma unroll
          for (int ks = 0; ks < 2; ++ks)
            acc[0][i2][0][j2] =
                __builtin_amdgcn_mfma_f32_16x16x32_bf16(a[i2][ks], b0[j2][ks], acc[0][i2][0][j2], 0, 0, 0);
      __builtin_amdgcn_s_setprio(0);
      __builtin_amdgcn_sched_barrier(0);
      asm volatile("s_barrier" ::: "memory");
    }

    // ---- phase 1: (mh=0, nh=1) — read b1(h1); a cached ----
    {
      const char* Bb = lds + sB1 * 16384;
#pragma unroll
      for (int j2 = 0; j2 < 2; ++j2)
#pragma unroll
        for (int ks = 0; ks < 2; ++ks) {
          const int byte = ((((wn * 2 + j2) * 16 + fr) * 128) + ks * 64 + fq * 16) ^ ((fr & 7) << 4);
          b1[j2][ks] = *reinterpret_cast<const bf16x8*>(Bb + byte);
        }
      stage(j0 + 1, sst); sst = (sst == 6) ? 0 : sst + 1;
      asm volatile("s_waitcnt vmcnt(6)" ::: "memory");
      asm volatile("s_barrier" ::: "memory");
      __builtin_amdgcn_sched_barrier(0);
      __builtin_amdgcn_s_setprio(1);
#pragma unroll
      for (int i2 = 0; i2 < 4; ++i2)
#pragma unroll
        for (int j2 = 0; j2 < 2; ++j2)
#pragma unroll
          for (int ks = 0; ks < 2; ++ks)
            acc[0][i2][1][j2] =
                __builtin_amdgcn_mfma_f32_16x16x32_bf16(a[i2][ks], b1[j2][ks], acc[0][i2][1][j2], 0, 0, 0);
      __builtin_amdgcn_s_setprio(0);
      __builtin_amdgcn_sched_barrier(0);
      asm volatile("s_barrier" ::: "memory");
    }

    // ---- phase 2: (mh=1, nh=0) — re-read a(h1); b0 cached ----
    {
      const char* Ab = lds + sA1 * 16384;
#pragma unroll
      for (int i2 = 0; i2 < 4; ++i2)
#pragma unroll
        for (int ks = 0; ks < 2; ++ks) {
          const int byte = ((((wm * 4 + i2) * 16 + fr) * 128) + ks * 64 + fq * 16) ^ ((fr & 7) << 4);
          a[i2][ks] = *reinterpret_cast<const bf16x8*>(Ab + byte);
        }
      stage(j0 + 2, sst); sst = (sst == 6) ? 0 : sst + 1;
      asm volatile("s_waitcnt vmcnt(6)" ::: "memory");
      asm volatile("s_barrier" ::: "memory");
      __builtin_amdgcn_sched_barrier(0);
      __builtin_amdgcn_s_setprio(1);
#pragma unroll
      for (int i2 = 0; i2 < 4; ++i2)
#pragma unroll
        for (int j2 = 0; j2 < 2; ++j2)
#pragma unroll
          for (int ks = 0; ks < 2; ++ks)
            acc[1][i2][0][j2] =
                __builtin_amdgcn_mfma_f32_16x16x32_bf16(a[i2][ks], b0[j2][ks], acc[1][i2][0][j2], 0, 0, 0);
      __builtin_amdgcn_s_setprio(0);
      __builtin_amdgcn_sched_barrier(0);
      asm volatile("s_barrier" ::: "memory");
    }

    // ---- phase 3: (mh=1, nh=1) — a and b1 cached, no ds_reads ----
    {
      stage(j0 + 3, sst); sst = (sst == 6) ? 0 : sst + 1;
      asm volatile("s_waitcnt vmcnt(6)" ::: "memory");
      asm volatile("s_barrier" ::: "memory");
      __builtin_amdgcn_sched_barrier(0);
      __builtin_amdgcn_s_setprio(1);
#pragma unroll
      for (int i2 = 0; i2 < 4; ++i2)
#pragma unroll
        for (int j2 = 0; j2 < 2; ++j2)
#pragma unroll
          for (int ks = 0; ks < 2; ++ks)
            acc[1][i2][1][j2] =
                __builtin_amdgcn_mfma_f32_16x16x32_bf16(a[i2][ks], b1[j2][ks], acc[1][i2][1][j2], 0, 0, 0);
      __builtin_amdgcn_s_setprio(0);
      __builtin_amdgcn_sched_barrier(0);
      asm volatile("s_barrier" ::: "memory");
    }

    sA0 += 4; if (sA0 >= 7) sA0 -= 7;
    sB0 += 4; if (sB0 >= 7) sB0 -= 7;
    sB1 += 4; if (sB1 >= 7) sB1 -= 7;
    sA1 += 4; if (sA1 >= 7) sA1 -= 7;
  }

  asm volatile("s_waitcnt vmcnt(0)" ::: "memory");  // drain tail dummies

  // epilogue: C/D layout col = lane&15, row = (lane>>4)*4 + r
#pragma unroll
  for (int mh = 0; mh < 2; ++mh)
#pragma unroll
    for (int i2 = 0; i2 < 4; ++i2) {
      const int rbase = row0 + (mh * 8 + wm * 4 + i2) * 16 + fq * 4;
#pragma unroll
      for (int nh = 0; nh < 2; ++nh)
#pragma unroll
        for (int j2 = 0; j2 < 2; ++j2) {
          const int col = col0 + (nh * 8 + wn * 2 + j2) * 16 + fr;
#pragma unroll
          for (int r = 0; r < 4; ++r) {
            const float v = acc[mh][i2][nh][j2][r];
            const int row = rbase + r;
            if (EPI == 0) {
              const int seg = col >> 11, cc = col & 2047;
              unsigned short* dst = (seg == 0) ? Qo : (seg == 1 ? Ko : Vo);
              dst[(size_t)row * 2048 + cc] = f2bf(v);
            } else {
              Cf[(size_t)row * N + col] = v + bias[col];
            }
          }
        }
    }
}

// --------- attention diag + V scale, one head strip (64 t-rows) per block ---------
__global__ __launch_bounds__(256, 2)
void attn_diag_ov(const unsigned short* __restrict__ Q, const unsigned short* __restrict__ K,
                  const unsigned short* __restrict__ V, unsigned short* __restrict__ OV) {
  __shared__ __align__(16) unsigned short qs[64 * 128];
  __shared__ __align__(16) unsigned short ks[128 * 128];
  __shared__ float dlds[64];
  const int tid = threadIdx.x;
  const int lane = tid & 63, wid = tid >> 6;
  const int head = blockIdx.y;            // b*16 + n
  const int b = head >> 4, n = head & 15;
  const int t0 = blockIdx.x << 6;
  const size_t hoff = (size_t)head << 18;
  const unsigned short* Qh = Q + hoff;
  const unsigned short* Kh = K + hoff;
  const unsigned short* Vh = V + hoff;

  const char* qsrc = (const char*)(Qh + ((size_t)t0 << 7));
#pragma unroll
  for (int i = 0; i < 4; ++i) {
    const int fb = (i * 256 + tid) << 4;
    const int sb = fb ^ (((fb >> 8) & 7) << 4);
    gload_lds16(qsrc + sb, (char*)qs + fb);
  }

  const int fr = lane & 15;
  const int fkb = (lane >> 4) << 4;
  const int g4 = (lane >> 4) << 2;

  float rsum[4] = {0.f, 0.f, 0.f, 0.f};
  float dnum[4] = {0.f, 0.f, 0.f, 0.f};
  const float scale = 0.02209708691207961f;  // 1/sqrt(2048)
  bf16x8 afrag[4];

  for (int jc = 0; jc < 2048; jc += 128) {
    const char* ksrc = (const char*)(Kh + ((size_t)jc << 7));
#pragma unroll
    for (int i = 0; i < 8; ++i) {
      const int fb = (i * 256 + tid) << 4;
      const int sb = fb ^ (((fb >> 8) & 7) << 4);
      gload_lds16(ksrc + sb, (char*)ks + fb);
    }
    __syncthreads();
    if (jc == 0) {
#pragma unroll
      for (int kk = 0; kk < 4; ++kk) {
        const int row = wid * 16 + fr;
        const int byte = (row << 8) + (kk << 6) + fkb;
        afrag[kk] = *reinterpret_cast<const bf16x8*>((const char*)qs + (byte ^ ((row & 7) << 4)));
      }
    }
#pragma unroll
    for (int jt = 0; jt < 8; ++jt) {
      f32x4 acc = {0.f, 0.f, 0.f, 0.f};
#pragma unroll
      for (int kk = 0; kk < 4; ++kk) {
        const int row = jt * 16 + fr;
        const int byte = (row << 8) + (kk << 6) + fkb;
        bf16x8 bfrag = *reinterpret_cast<const bf16x8*>((const char*)ks + (byte ^ ((row & 7) << 4)));
        acc = __builtin_amdgcn_mfma_f32_16x16x32_bf16(afrag[kk], bfrag, acc, 0, 0, 0);
      }
      const int colj = jc + jt * 16 + fr;
      const int rowt = t0 + wid * 16 + g4;
#pragma unroll
      for (int r = 0; r < 4; ++r) {
        const float e = __expf(acc[r] * scale);
        rsum[r] += e;
        if (colj == rowt + r) dnum[r] = e;
      }
    }
    __syncthreads();
  }

#pragma unroll
  for (int r = 0; r < 4; ++r) {
#pragma unroll
    for (int s = 1; s < 16; s <<= 1) {
      rsum[r] += __shfl_xor(rsum[r], s, 64);
      dnum[r] += __shfl_xor(dnum[r], s, 64);
    }
  }
  if (fr == 0) {
#pragma unroll
    for (int r = 0; r < 4; ++r)
      dlds[wid * 16 + g4 + r] = dnum[r] / rsum[r];
  }
  __syncthreads();

  const unsigned short* vsrc = Vh + ((size_t)t0 << 7);
  unsigned short* dst = OV + ((size_t)((b << 11) + t0)) * 2048 + (n << 7);
#pragma unroll
  for (int c = 0; c < 4; ++c) {
    const int flat = (c * 256 + tid) << 3;
    const int row = flat >> 7, col = flat & 127;
    bf16x8 v = *reinterpret_cast<const bf16x8*>(vsrc + flat);
    const float d = dlds[row];
    bf16x8 o;
#pragma unroll
    for (int e = 0; e < 8; ++e)
      o[e] = (short)f2bf(bf2f((unsigned short)v[e]) * d);
    *reinterpret_cast<bf16x8*>(dst + (size_t)row * 2048 + col) = o;
  }
}

extern "C" void kernel_launch(void* const* d_in, const int* in_sizes, int n_in,
                              void* d_out, int out_size, void* d_ws, size_t ws_size,
                              hipStream_t stream) {
  const float* x = (const float*)d_in[0];        // (4,2048,2048)
  const float* w_qkv = (const float*)d_in[1];    // (2048,6144)
  const float* w_proj = (const float*)d_in[2];   // (2048,2048)
  const float* b_proj = (const float*)d_in[3];   // (2048,)
  float* out = (float*)d_out;                    // (4,2048,2048) f32

  char* p = (char*)d_ws;
  unsigned short* Xb = (unsigned short*)p;     p += (size_t)8192 * 2048 * 2;
  unsigned short* WqkvT = (unsigned short*)p;  p += (size_t)6144 * 2048 * 2;
  unsigned short* WprojT = (unsigned short*)p; p += (size_t)2048 * 2048 * 2;
  unsigned short* Qb = (unsigned short*)p;     p += (size_t)8192 * 2048 * 2;
  unsigned short* Kb = (unsigned short*)p;     p += (size_t)8192 * 2048 * 2;
  unsigned short* Vb = (unsigned short*)p;     p += (size_t)8192 * 2048 * 2;
  unsigned short* OV = (unsigned short*)p;     p += (size_t)8192 * 2048 * 2;

  // allow 128 KiB dynamic LDS (persistent function attribute; safe to repeat)
  (void)hipFuncSetAttribute((const void*)gemm256<0>,
                            hipFuncAttributeMaxDynamicSharedMemorySize, 131072);
  (void)hipFuncSetAttribute((const void*)gemm256<1>,
                            hipFuncAttributeMaxDynamicSharedMemorySize, 131072);

  cast_f32_bf16<<<16384, 256, 0, stream>>>(x, Xb);
  transpose_cast<<<dim3(192, 64), dim3(32, 8), 0, stream>>>(w_qkv, WqkvT, 2048, 6144);
  transpose_cast<<<dim3(64, 64), dim3(32, 8), 0, stream>>>(w_proj, WprojT, 2048, 2048);

  // QKV = Xb (8192x2048) * WqkvT^T -> split bf16 Q/K/V (B,T,D)
  gemm256<0><<<dim3(32 * 24), 512, 131072, stream>>>(Xb, WqkvT, Qb, Kb, Vb, nullptr, nullptr,
                                                     8192, 6144, 2048);
  // diag softmax + V scale -> OV (8192x2048) bf16
  attn_diag_ov<<<dim3(32, 64), 256, 0, stream>>>(Qb, Kb, Vb, OV);
  // out = OV * WprojT^T + b_proj (f32)
  gemm256<1><<<dim3(32 * 8), 512, 131072, stream>>>(OV, WprojT, nullptr, nullptr, nullptr, out,
                                                    b_proj, 8192, 2048, 2048);
}

// Round 5
// 393.510 us; speedup vs baseline: 1.2197x; 1.0482x over previous
//
#include <hip/hip_runtime.h>
#include <hip/hip_bf16.h>

typedef short bf16x8 __attribute__((ext_vector_type(8)));
typedef float f32x4 __attribute__((ext_vector_type(4)));

__device__ __forceinline__ unsigned short f2bf(float f) {
  union { float f; unsigned int u; } x; x.f = f;
  return (unsigned short)((x.u + 0x7fffu + ((x.u >> 16) & 1u)) >> 16);
}
__device__ __forceinline__ float bf2f(unsigned short u) {
  union { unsigned int u; float f; } x; x.u = ((unsigned int)u) << 16;
  return x.f;
}
__device__ __forceinline__ void gload_lds16(const void* g, void* l) {
  __builtin_amdgcn_global_load_lds((const __attribute__((address_space(1))) void*)g,
                                   (__attribute__((address_space(3))) void*)l, 16, 0, 0);
}

// ---------------- cast x (f32 -> bf16), 4 elems/thread ----------------
__global__ void cast_f32_bf16(const float* __restrict__ src, unsigned short* __restrict__ dst) {
  int i = blockIdx.x * blockDim.x + threadIdx.x;
  float4 v = reinterpret_cast<const float4*>(src)[i];
  ushort4 o;
  o.x = f2bf(v.x); o.y = f2bf(v.y); o.z = f2bf(v.z); o.w = f2bf(v.w);
  reinterpret_cast<ushort4*>(dst)[i] = o;
}

// ------------- transpose+cast: src (R x C) f32 -> dst (C x R) bf16 -------------
__global__ void transpose_cast(const float* __restrict__ src, unsigned short* __restrict__ dst,
                               int R, int C) {
  __shared__ float tile[32][33];
  int c0 = blockIdx.x * 32, r0 = blockIdx.y * 32;
  int tx = threadIdx.x, ty = threadIdx.y;  // 32 x 8
#pragma unroll
  for (int i = 0; i < 4; ++i)
    tile[ty + i * 8][tx] = src[(size_t)(r0 + ty + i * 8) * C + (c0 + tx)];
  __syncthreads();
#pragma unroll
  for (int i = 0; i < 4; ++i)
    dst[(size_t)(c0 + ty + i * 8) * R + (r0 + tx)] = f2bf(tile[tx][ty + i * 8]);
}

// ============ 256x256 GEMM, half-tile RING-7 pipeline, 1 barrier/phase ============
// 512 threads = 8 waves (2M x 4N). BK=64. LDS = 8 slots x 16 KB = 128 KiB dynamic.
// Half-tile stream j = 4t+ht, ht: 0=A.h0 1=B.h0 2=B.h1 3=A.h1 (first-reader order).
// Half j -> slot j%7, staged at global phase j-5. Slot 7 = tail-dummy scratch.
// Phase structure: [ds_reads; stage(j); vmcnt(6); s_barrier; setprio(1); MFMA; setprio(0)].
// NO second barrier, NO sched_barrier: LDS-reads of each half happen only at its
// first-touch phase (A.h0@p0, B.h0@p0, B.h1@p1, A.h1@p2; later uses are from regs),
// and its overwriter is staged >=3 phases later -> read-issue and overwrite-issue are
// always >=2 barriers apart. Writer's vmcnt(6) (3 halves in flight) drains each half
// 3 phases after issue, >=1 barrier before any reader -> no RAW/WAR races.
// Single barrier lets waves drift: one wave's MFMA overlaps others' ds_reads, and the
// compiler may hoist phase p+1's independent ds_reads into phase p's MFMA cluster.
// Swizzle (T2): row r (128B) holds 16B-chunk s at byte (s^(r&7))*16.
// EPI 0: bf16 split into Q/K/V (B,T,D). EPI 1: f32 + bias.
template <int EPI>
__global__ __launch_bounds__(512, 2)
void gemm256(const unsigned short* __restrict__ A, const unsigned short* __restrict__ Bt,
             unsigned short* __restrict__ Qo, unsigned short* __restrict__ Ko,
             unsigned short* __restrict__ Vo, float* __restrict__ Cf,
             const float* __restrict__ bias, int M, int N, int K) {
  extern __shared__ __align__(16) char lds[];
  const int tid = threadIdx.x;
  const int lane = tid & 63, wid = tid >> 6;
  const int wm = wid >> 2, wn = wid & 3;
  const int fr = lane & 15, fq = lane >> 4;

  // XCD swizzle (gridDim.x % 8 == 0 for both shapes)
  const int nbn = N >> 8;
  const int cpx = gridDim.x >> 3;
  const int id = blockIdx.x;
  const int sw = (id & 7) * cpx + (id >> 3);
  const int bm = sw / nbn, bn = sw % nbn;
  const int row0 = bm << 8, col0 = bn << 8;

  const int NT = K >> 6;

  // staging: thread covers row srow (+64 for 2nd issue), 16B at XOR-pre-swizzled col
  const int srow = tid >> 3;
  const int scol = ((tid & 7) ^ (srow & 7)) << 3;  // elems

  auto stage = [&](int j, int slot) {
    if (j < 4 * NT) {
      const int t = j >> 2, ht = j & 3;
      const int isB = (ht == 1 || ht == 2);
      const int h = (ht >= 2) ? 1 : 0;
      const unsigned short* base = isB ? Bt : A;
      const int grow = (isB ? col0 : row0) + h * 128 + srow;
      const unsigned short* src = base + (size_t)grow * K + t * 64 + scol;
      char* l0 = lds + slot * 16384 + tid * 16;
      gload_lds16(src, l0);
      gload_lds16(src + (size_t)64 * K, l0 + 8192);
    } else {
      // tail dummy: keep vmcnt stream uniform; lands in scratch slot 7
      char* l0 = lds + 7 * 16384 + tid * 16;
      gload_lds16(A + (tid << 3), l0);
      gload_lds16(A + (tid << 3), l0 + 8192);
    }
  };

  f32x4 acc[2][4][2][2] = {};

  // prologue: halves j=0..4 -> slots 0..4; vmcnt(6) forces j=0,1 landed (phase-0 reads)
  stage(0, 0); stage(1, 1); stage(2, 2); stage(3, 3); stage(4, 4);
  asm volatile("s_waitcnt vmcnt(6)" ::: "memory");
  asm volatile("s_barrier" ::: "memory");

  int sA0 = 0, sB0 = 1, sB1 = 2, sA1 = 3, sst = 5;

  for (int k = 0; k < NT; ++k) {
    const int j0 = 4 * k + 5;
    bf16x8 a[4][2], b0[2][2], b1[2][2];

    // ---- phase 0: (mh=0, nh=0) — LDS-read a(h0), b0(h0) ----
    {
      const char* Ab = lds + sA0 * 16384;
      const char* Bb = lds + sB0 * 16384;
#pragma unroll
      for (int i2 = 0; i2 < 4; ++i2)
#pragma unroll
        for (int ks = 0; ks < 2; ++ks) {
          const int byte = ((((wm * 4 + i2) * 16 + fr) * 128) + ks * 64 + fq * 16) ^ ((fr & 7) << 4);
          a[i2][ks] = *reinterpret_cast<const bf16x8*>(Ab + byte);
        }
#pragma unroll
      for (int j2 = 0; j2 < 2; ++j2)
#pragma unroll
        for (int ks = 0; ks < 2; ++ks) {
          const int byte = ((((wn * 2 + j2) * 16 + fr) * 128) + ks * 64 + fq * 16) ^ ((fr & 7) << 4);
          b0[j2][ks] = *reinterpret_cast<const bf16x8*>(Bb + byte);
        }
      stage(j0 + 0, sst); sst = (sst == 6) ? 0 : sst + 1;
      asm volatile("s_waitcnt vmcnt(6)" ::: "memory");
      asm volatile("s_barrier" ::: "memory");
      __builtin_amdgcn_s_setprio(1);
#pragma unroll
      for (int i2 = 0; i2 < 4; ++i2)
#pragma unroll
        for (int j2 = 0; j2 < 2; ++j2)
#pragma unroll
          for (int ks = 0; ks < 2; ++ks)
            acc[0][i2][0][j2] =
                __builtin_amdgcn_mfma_f32_16x16x32_bf16(a[i2][ks], b0[j2][ks], acc[0][i2][0][j2], 0, 0, 0);
      __builtin_amdgcn_s_setprio(0);
    }

    // ---- phase 1: (mh=0, nh=1) — LDS-read b1(h1); a cached ----
    {
      const char* Bb = lds + sB1 * 16384;
#pragma unroll
      for (int j2 = 0; j2 < 2; ++j2)
#pragma unroll
        for (int ks = 0; ks < 2; ++ks) {
          const int byte = ((((wn * 2 + j2) * 16 + fr) * 128) + ks * 64 + fq * 16) ^ ((fr & 7) << 4);
          b1[j2][ks] = *reinterpret_cast<const bf16x8*>(Bb + byte);
        }
      stage(j0 + 1, sst); sst = (sst == 6) ? 0 : sst + 1;
      asm volatile("s_waitcnt vmcnt(6)" ::: "memory");
      asm volatile("s_barrier" ::: "memory");
      __builtin_amdgcn_s_setprio(1);
#pragma unroll
      for (int i2 = 0; i2 < 4; ++i2)
#pragma unroll
        for (int j2 = 0; j2 < 2; ++j2)
#pragma unroll
          for (int ks = 0; ks < 2; ++ks)
            acc[0][i2][1][j2] =
                __builtin_amdgcn_mfma_f32_16x16x32_bf16(a[i2][ks], b1[j2][ks], acc[0][i2][1][j2], 0, 0, 0);
      __builtin_amdgcn_s_setprio(0);
    }

    // ---- phase 2: (mh=1, nh=0) — LDS-read a(h1); b0 cached ----
    {
      const char* Ab = lds + sA1 * 16384;
#pragma unroll
      for (int i2 = 0; i2 < 4; ++i2)
#pragma unroll
        for (int ks = 0; ks < 2; ++ks) {
          const int byte = ((((wm * 4 + i2) * 16 + fr) * 128) + ks * 64 + fq * 16) ^ ((fr & 7) << 4);
          a[i2][ks] = *reinterpret_cast<const bf16x8*>(Ab + byte);
        }
      stage(j0 + 2, sst); sst = (sst == 6) ? 0 : sst + 1;
      asm volatile("s_waitcnt vmcnt(6)" ::: "memory");
      asm volatile("s_barrier" ::: "memory");
      __builtin_amdgcn_s_setprio(1);
#pragma unroll
      for (int i2 = 0; i2 < 4; ++i2)
#pragma unroll
        for (int j2 = 0; j2 < 2; ++j2)
#pragma unroll
          for (int ks = 0; ks < 2; ++ks)
            acc[1][i2][0][j2] =
                __builtin_amdgcn_mfma_f32_16x16x32_bf16(a[i2][ks], b0[j2][ks], acc[1][i2][0][j2], 0, 0, 0);
      __builtin_amdgcn_s_setprio(0);
    }

    // ---- phase 3: (mh=1, nh=1) — a and b1 cached, no LDS reads ----
    {
      stage(j0 + 3, sst); sst = (sst == 6) ? 0 : sst + 1;
      asm volatile("s_waitcnt vmcnt(6)" ::: "memory");
      asm volatile("s_barrier" ::: "memory");
      __builtin_amdgcn_s_setprio(1);
#pragma unroll
      for (int i2 = 0; i2 < 4; ++i2)
#pragma unroll
        for (int j2 = 0; j2 < 2; ++j2)
#pragma unroll
          for (int ks = 0; ks < 2; ++ks)
            acc[1][i2][1][j2] =
                __builtin_amdgcn_mfma_f32_16x16x32_bf16(a[i2][ks], b1[j2][ks], acc[1][i2][1][j2], 0, 0, 0);
      __builtin_amdgcn_s_setprio(0);
    }

    sA0 += 4; if (sA0 >= 7) sA0 -= 7;
    sB0 += 4; if (sB0 >= 7) sB0 -= 7;
    sB1 += 4; if (sB1 >= 7) sB1 -= 7;
    sA1 += 4; if (sA1 >= 7) sA1 -= 7;
  }

  asm volatile("s_waitcnt vmcnt(0)" ::: "memory");  // drain tail dummies

  // epilogue: C/D layout col = lane&15, row = (lane>>4)*4 + r
#pragma unroll
  for (int mh = 0; mh < 2; ++mh)
#pragma unroll
    for (int i2 = 0; i2 < 4; ++i2) {
      const int rbase = row0 + (mh * 8 + wm * 4 + i2) * 16 + fq * 4;
#pragma unroll
      for (int nh = 0; nh < 2; ++nh)
#pragma unroll
        for (int j2 = 0; j2 < 2; ++j2) {
          const int col = col0 + (nh * 8 + wn * 2 + j2) * 16 + fr;
#pragma unroll
          for (int r = 0; r < 4; ++r) {
            const float v = acc[mh][i2][nh][j2][r];
            const int row = rbase + r;
            if (EPI == 0) {
              const int seg = col >> 11, cc = col & 2047;
              unsigned short* dst = (seg == 0) ? Qo : (seg == 1 ? Ko : Vo);
              dst[(size_t)row * 2048 + cc] = f2bf(v);
            } else {
              Cf[(size_t)row * N + col] = v + bias[col];
            }
          }
        }
    }
}

// --------- attention diag + V scale, one head strip (64 t-rows) per block ---------
__global__ __launch_bounds__(256, 2)
void attn_diag_ov(const unsigned short* __restrict__ Q, const unsigned short* __restrict__ K,
                  const unsigned short* __restrict__ V, unsigned short* __restrict__ OV) {
  __shared__ __align__(16) unsigned short qs[64 * 128];
  __shared__ __align__(16) unsigned short ks[128 * 128];
  __shared__ float dlds[64];
  const int tid = threadIdx.x;
  const int lane = tid & 63, wid = tid >> 6;
  const int head = blockIdx.y;            // b*16 + n
  const int b = head >> 4, n = head & 15;
  const int t0 = blockIdx.x << 6;
  const size_t hoff = (size_t)head << 18;
  const unsigned short* Qh = Q + hoff;
  const unsigned short* Kh = K + hoff;
  const unsigned short* Vh = V + hoff;

  const char* qsrc = (const char*)(Qh + ((size_t)t0 << 7));
#pragma unroll
  for (int i = 0; i < 4; ++i) {
    const int fb = (i * 256 + tid) << 4;
    const int sb = fb ^ (((fb >> 8) & 7) << 4);
    gload_lds16(qsrc + sb, (char*)qs + fb);
  }

  const int fr = lane & 15;
  const int fkb = (lane >> 4) << 4;
  const int g4 = (lane >> 4) << 2;

  float rsum[4] = {0.f, 0.f, 0.f, 0.f};
  float dnum[4] = {0.f, 0.f, 0.f, 0.f};
  const float scale = 0.02209708691207961f;  // 1/sqrt(2048)
  bf16x8 afrag[4];

  for (int jc = 0; jc < 2048; jc += 128) {
    const char* ksrc = (const char*)(Kh + ((size_t)jc << 7));
#pragma unroll
    for (int i = 0; i < 8; ++i) {
      const int fb = (i * 256 + tid) << 4;
      const int sb = fb ^ (((fb >> 8) & 7) << 4);
      gload_lds16(ksrc + sb, (char*)ks + fb);
    }
    __syncthreads();
    if (jc == 0) {
#pragma unroll
      for (int kk = 0; kk < 4; ++kk) {
        const int row = wid * 16 + fr;
        const int byte = (row << 8) + (kk << 6) + fkb;
        afrag[kk] = *reinterpret_cast<const bf16x8*>((const char*)qs + (byte ^ ((row & 7) << 4)));
      }
    }
#pragma unroll
    for (int jt = 0; jt < 8; ++jt) {
      f32x4 acc = {0.f, 0.f, 0.f, 0.f};
#pragma unroll
      for (int kk = 0; kk < 4; ++kk) {
        const int row = jt * 16 + fr;
        const int byte = (row << 8) + (kk << 6) + fkb;
        bf16x8 bfrag = *reinterpret_cast<const bf16x8*>((const char*)ks + (byte ^ ((row & 7) << 4)));
        acc = __builtin_amdgcn_mfma_f32_16x16x32_bf16(afrag[kk], bfrag, acc, 0, 0, 0);
      }
      const int colj = jc + jt * 16 + fr;
      const int rowt = t0 + wid * 16 + g4;
#pragma unroll
      for (int r = 0; r < 4; ++r) {
        const float e = __expf(acc[r] * scale);
        rsum[r] += e;
        if (colj == rowt + r) dnum[r] = e;
      }
    }
    __syncthreads();
  }

#pragma unroll
  for (int r = 0; r < 4; ++r) {
#pragma unroll
    for (int s = 1; s < 16; s <<= 1) {
      rsum[r] += __shfl_xor(rsum[r], s, 64);
      dnum[r] += __shfl_xor(dnum[r], s, 64);
    }
  }
  if (fr == 0) {
#pragma unroll
    for (int r = 0; r < 4; ++r)
      dlds[wid * 16 + g4 + r] = dnum[r] / rsum[r];
  }
  __syncthreads();

  const unsigned short* vsrc = Vh + ((size_t)t0 << 7);
  unsigned short* dst = OV + ((size_t)((b << 11) + t0)) * 2048 + (n << 7);
#pragma unroll
  for (int c = 0; c < 4; ++c) {
    const int flat = (c * 256 + tid) << 3;
    const int row = flat >> 7, col = flat & 127;
    bf16x8 v = *reinterpret_cast<const bf16x8*>(vsrc + flat);
    const float d = dlds[row];
    bf16x8 o;
#pragma unroll
    for (int e = 0; e < 8; ++e)
      o[e] = (short)f2bf(bf2f((unsigned short)v[e]) * d);
    *reinterpret_cast<bf16x8*>(dst + (size_t)row * 2048 + col) = o;
  }
}

extern "C" void kernel_launch(void* const* d_in, const int* in_sizes, int n_in,
                              void* d_out, int out_size, void* d_ws, size_t ws_size,
                              hipStream_t stream) {
  const float* x = (const float*)d_in[0];        // (4,2048,2048)
  const float* w_qkv = (const float*)d_in[1];    // (2048,6144)
  const float* w_proj = (const float*)d_in[2];   // (2048,2048)
  const float* b_proj = (const float*)d_in[3];   // (2048,)
  float* out = (float*)d_out;                    // (4,2048,2048) f32

  char* p = (char*)d_ws;
  unsigned short* Xb = (unsigned short*)p;     p += (size_t)8192 * 2048 * 2;
  unsigned short* WqkvT = (unsigned short*)p;  p += (size_t)6144 * 2048 * 2;
  unsigned short* WprojT = (unsigned short*)p; p += (size_t)2048 * 2048 * 2;
  unsigned short* Qb = (unsigned short*)p;     p += (size_t)8192 * 2048 * 2;
  unsigned short* Kb = (unsigned short*)p;     p += (size_t)8192 * 2048 * 2;
  unsigned short* Vb = (unsigned short*)p;     p += (size_t)8192 * 2048 * 2;
  unsigned short* OV = (unsigned short*)p;     p += (size_t)8192 * 2048 * 2;

  // allow 128 KiB dynamic LDS (persistent function attribute; safe to repeat)
  (void)hipFuncSetAttribute((const void*)gemm256<0>,
                            hipFuncAttributeMaxDynamicSharedMemorySize, 131072);
  (void)hipFuncSetAttribute((const void*)gemm256<1>,
                            hipFuncAttributeMaxDynamicSharedMemorySize, 131072);

  cast_f32_bf16<<<16384, 256, 0, stream>>>(x, Xb);
  transpose_cast<<<dim3(192, 64), dim3(32, 8), 0, stream>>>(w_qkv, WqkvT, 2048, 6144);
  transpose_cast<<<dim3(64, 64), dim3(32, 8), 0, stream>>>(w_proj, WprojT, 2048, 2048);

  // QKV = Xb (8192x2048) * WqkvT^T -> split bf16 Q/K/V (B,T,D)
  gemm256<0><<<dim3(32 * 24), 512, 131072, stream>>>(Xb, WqkvT, Qb, Kb, Vb, nullptr, nullptr,
                                                     8192, 6144, 2048);
  // diag softmax + V scale -> OV (8192x2048) bf16
  attn_diag_ov<<<dim3(32, 64), 256, 0, stream>>>(Qb, Kb, Vb, OV);
  // out = OV * WprojT^T + b_proj (f32)
  gemm256<1><<<dim3(32 * 8), 512, 131072, stream>>>(OV, WprojT, nullptr, nullptr, nullptr, out,
                                                    b_proj, 8192, 2048, 2048);
}